// Round 3
// baseline (3443.875 us; speedup 1.0000x reference)
//
#include <hip/hip_runtime.h>
#include <hip/hip_bf16.h>
#include <math.h>

#define B_SZ   32
#define NXX    16384
#define IN_DIM 3
#define DIM    64
#define JM     16
#define MODE   128
#define RANKK  4
#define FC_DIM 128
#define N_LAY  3

typedef __attribute__((ext_vector_type(8))) short bf16x8;
typedef __attribute__((ext_vector_type(4))) float f32x4;
typedef unsigned short u16;

__device__ __forceinline__ float gelu_exact(float v) {
    return 0.5f * v * (1.0f + erff(v * 0.70710678118654752f));
}
__device__ __forceinline__ float bf2f(u16 u) {
    return __uint_as_float((unsigned)u << 16);
}
__device__ __forceinline__ void split_bf16(float v, u16& h, u16& l) {
    __hip_bfloat16 bh = __float2bfloat16(v);
    float fh = __bfloat162float(bh);
    __hip_bfloat16 bl = __float2bfloat16(v - fh);
    h = *(u16*)&bh;
    l = *(u16*)&bl;
}

// ---------------------------------------------------------------------------
__global__ __launch_bounds__(256) void k_zero(float* __restrict__ p, int n) {
    int i = blockIdx.x * 256 + threadIdx.x;
    if (i < n) p[i] = 0.f;
}

// H[j,k,l] = D_out[j,k]*D_in[j,l]*product[k,l] + sum_r A[j,r,k]*Bm[j,r,l]
__global__ __launch_bounds__(256) void k_build_H(
        const float* __restrict__ Dout, const float* __restrict__ Din,
        const float* __restrict__ product, const float* __restrict__ A,
        const float* __restrict__ Bm, float* __restrict__ H) {
    int idx = blockIdx.x * 256 + threadIdx.x;
    int j = idx >> 14;
    int k = (idx >> 7) & 127;
    int l = idx & 127;
    float v = Dout[j * MODE + k] * Din[j * MODE + l] * product[k * MODE + l];
#pragma unroll
    for (int r = 0; r < RANKK; ++r)
        v += A[(j * RANKK + r) * MODE + k] * Bm[(j * RANKK + r) * MODE + l];
    H[idx] = v;
}

// bases (fp32 [x][k]) -> hi/lo bf16 planes, same layout.  grid 8192 x 256
__global__ __launch_bounds__(256) void k_setup_bases(
        const float* __restrict__ bases, u16* __restrict__ bh, u16* __restrict__ bl) {
    int i = blockIdx.x * 256 + threadIdx.x;
    u16 h, l;
    split_bf16(bases[i], h, l);
    bh[i] = h; bl[i] = l;
}

// W1T[f*64+c] = W1[c*128+f] hi/lo.  grid 32 x 256
__global__ __launch_bounds__(256) void k_setup_w1t(
        const float* __restrict__ W1, u16* __restrict__ wh, u16* __restrict__ wl) {
    int i = blockIdx.x * 256 + threadIdx.x;   // i = f*64 + c
    int f = i >> 6, c = i & 63;
    u16 h, l;
    split_bf16(W1[c * FC_DIM + f], h, l);
    wh[i] = h; wl[i] = l;
}

// fc0: h[b,x,c] = sum_d x[b,x,d]*W0[d,c] + b0[c]   grid (256, 32) x 64 (1 wave)
__global__ __launch_bounds__(64) void k_fc0(
        const float* __restrict__ x, const float* __restrict__ W0,
        const float* __restrict__ b0, u16* __restrict__ hh, u16* __restrict__ hl) {
    int lane = threadIdx.x;             // lane = c
    int b = blockIdx.y;
    int x0 = blockIdx.x * 64;
    float w0 = W0[0 * DIM + lane], w1 = W0[1 * DIM + lane], w2 = W0[2 * DIM + lane];
    float bb = b0[lane];
    for (int xx = 0; xx < 64; ++xx) {
        const float* xp = x + ((size_t)b * NXX + x0 + xx) * IN_DIM;  // uniform -> s_load
        float v = xp[0] * w0 + xp[1] * w1 + xp[2] * w2 + bb;
        u16 h, l;
        split_bf16(v, h, l);
        size_t o = ((size_t)(b << 14) + x0 + xx) * 64 + lane;
        hh[o] = h; hl[o] = l;
    }
}

// Spectral: xh[b,c,l] += sum_x h[b,x,c]*wbases[x,l]  (atomic partials)
// grid (64, 32, 4) x 64: block = 1 wave, lane=c, x-slice 256, mode group l0=z*32.
// wbases index is blockIdx/loop-derived only -> scalar loads.
__global__ __launch_bounds__(64) void k_spectral(
        const u16* __restrict__ Hh, const u16* __restrict__ Hl,
        const float* __restrict__ wbases, float* __restrict__ xh) {
    int lane = threadIdx.x;             // c
    int b = blockIdx.y;
    int l0 = blockIdx.z * 32;
    int xs = blockIdx.x * 256;
    float acc[32] = {};
    const u16* ph = Hh + ((size_t)(b << 14) + xs) * 64 + lane;
    const u16* pl = Hl + ((size_t)(b << 14) + xs) * 64 + lane;
    const float* wb = wbases + (size_t)xs * MODE + l0;
#pragma unroll 2
    for (int xx = 0; xx < 256; ++xx) {
        float v = bf2f(ph[(size_t)xx << 6]) + bf2f(pl[(size_t)xx << 6]);
        const float* w = wb + ((size_t)xx << 7);
#pragma unroll
        for (int ll = 0; ll < 32; ++ll) acc[ll] += v * w[ll];
    }
    float* xp = xh + ((size_t)b * 64 + lane) * MODE + l0;
#pragma unroll
    for (int ll = 0; ll < 32; ++ll) atomicAdd(xp + ll, acc[ll]);
}

// Fused H-mix + channel contraction (unchanged structure from R2).
// grid (32, 16) x 256
__global__ __launch_bounds__(256) void k_hmix(
        const float* __restrict__ xh, const float* __restrict__ H,
        const float* __restrict__ Wsp, float* __restrict__ y, int lay) {
    __shared__ float xs[DIM][132];
    __shared__ float Ts[DIM][MODE];
    __shared__ float Ws[DIM][DIM];
    int t = threadIdx.x;
    int b = blockIdx.x;
    int j = blockIdx.y;
    const float* xb = xh + (size_t)b * DIM * MODE;
    for (int idx = t; idx < DIM * MODE; idx += 256)
        xs[idx >> 7][idx & 127] = xb[idx];
    const float* Wl = Wsp + (size_t)lay * DIM * DIM * JM + j;
    for (int idx = t; idx < DIM * DIM; idx += 256)
        Ws[idx >> 6][idx & 63] = Wl[(size_t)idx * JM];
    __syncthreads();
    {
        int k4 = (t & 31) * 4;
        int i0 = (t >> 5) * 8;
        float acc[8][4] = {};
        const float* Hbase = H + ((size_t)j * MODE + k4) * MODE;
        for (int l = 0; l < MODE; l += 4) {
            float4 hv0 = *(const float4*)(Hbase + 0 * MODE + l);
            float4 hv1 = *(const float4*)(Hbase + 1 * MODE + l);
            float4 hv2 = *(const float4*)(Hbase + 2 * MODE + l);
            float4 hv3 = *(const float4*)(Hbase + 3 * MODE + l);
#pragma unroll
            for (int ii = 0; ii < 8; ++ii) {
                float4 xv = *(const float4*)&xs[i0 + ii][l];
                acc[ii][0] += hv0.x * xv.x + hv0.y * xv.y + hv0.z * xv.z + hv0.w * xv.w;
                acc[ii][1] += hv1.x * xv.x + hv1.y * xv.y + hv1.z * xv.z + hv1.w * xv.w;
                acc[ii][2] += hv2.x * xv.x + hv2.y * xv.y + hv2.z * xv.z + hv2.w * xv.w;
                acc[ii][3] += hv3.x * xv.x + hv3.y * xv.y + hv3.z * xv.z + hv3.w * xv.w;
            }
        }
#pragma unroll
        for (int ii = 0; ii < 8; ++ii)
            *(float4*)&Ts[i0 + ii][k4] = make_float4(acc[ii][0], acc[ii][1], acc[ii][2], acc[ii][3]);
    }
    __syncthreads();
    {
        int k = t & 127;
        int o0 = (t >> 7) * 32;
        float acc2[32] = {};
        for (int i = 0; i < DIM; ++i) {
            float tv = Ts[i][k];
            const float* wr = &Ws[i][o0];
#pragma unroll
            for (int o4 = 0; o4 < 32; o4 += 4) {
                float4 wv = *(const float4*)(wr + o4);
                acc2[o4 + 0] += wv.x * tv;
                acc2[o4 + 1] += wv.y * tv;
                acc2[o4 + 2] += wv.z * tv;
                acc2[o4 + 3] += wv.w * tv;
            }
        }
        float* yp = y + ((size_t)b * DIM + o0) * MODE + k;
#pragma unroll
        for (int o = 0; o < 32; ++o)
            atomicAdd(yp + (size_t)o * MODE, acc2[o]);
    }
}

// Abuf[b][o][kk] = kk<128 ? y[b,o,kk] : Wconv[lay][o][kk-128], split hi/lo.
// grid (32) x 256
__global__ __launch_bounds__(256) void k_build_A(
        const float* __restrict__ y, const float* __restrict__ Wconv,
        u16* __restrict__ Ah, u16* __restrict__ Al, int lay) {
    int b = blockIdx.x;
    for (int idx = threadIdx.x; idx < DIM * 192; idx += 256) {
        int o = idx / 192, kk = idx % 192;
        float v = (kk < 128) ? y[((size_t)b * DIM + o) * MODE + kk]
                             : Wconv[(size_t)lay * DIM * DIM + o * DIM + (kk - 128)];
        u16 h, l;
        split_bf16(v, h, l);
        size_t off = ((size_t)b * DIM + o) * 192 + kk;
        Ah[off] = h; Al[off] = l;
    }
}

// Split-bf16 MFMA: h[b,o,x] = act( A(64x192) @ B(192x_xtile) + bconv )
//   A = [y | Wconv] hi/lo,  B rows: kk<128 -> bases[x][kk], kk>=128 -> h[b][x][c]
// In-place on h planes: each wave owns disjoint x range (reads before writes,
// wave-lockstep => safe).  grid (64, 32) x 256 (4 waves; wave = 64 x).
__global__ __launch_bounds__(256, 2) void k_inv_conv_mfma(
        const u16* __restrict__ Ah, const u16* __restrict__ Al,
        const u16* __restrict__ Bh, const u16* __restrict__ Bl,
        u16* __restrict__ Hh, u16* __restrict__ Hl,
        const float* __restrict__ bconv, int lay, int do_act) {
    int t = threadIdx.x;
    int wave = t >> 6, lane = t & 63, quad = lane >> 4, l16 = lane & 15;
    int b = blockIdx.y;
    int xw = blockIdx.x * 256 + wave * 64;
    f32x4 acc[4][4] = {};
#pragma unroll
    for (int ks = 0; ks < 6; ++ks) {
        int k0 = ks * 32;
        bf16x8 afh[4], afl[4], bfh[4], bfl[4];
#pragma unroll
        for (int ot = 0; ot < 4; ++ot) {
            size_t ao = ((size_t)(b * 64 + ot * 16 + l16)) * 192 + k0 + quad * 8;
            afh[ot] = *(const bf16x8*)(Ah + ao);
            afl[ot] = *(const bf16x8*)(Al + ao);
        }
#pragma unroll
        for (int xt = 0; xt < 4; ++xt) {
            int x = xw + xt * 16 + l16;
            if (ks < 4) {
                size_t bo = (size_t)x * MODE + k0 + quad * 8;
                bfh[xt] = *(const bf16x8*)(Bh + bo);
                bfl[xt] = *(const bf16x8*)(Bl + bo);
            } else {
                size_t bo = ((size_t)(b << 14) + x) * 64 + (k0 - 128) + quad * 8;
                bfh[xt] = *(const bf16x8*)(Hh + bo);
                bfl[xt] = *(const bf16x8*)(Hl + bo);
            }
        }
#pragma unroll
        for (int ot = 0; ot < 4; ++ot)
#pragma unroll
            for (int xt = 0; xt < 4; ++xt) {
                acc[ot][xt] = __builtin_amdgcn_mfma_f32_16x16x32_bf16(afh[ot], bfl[xt], acc[ot][xt], 0, 0, 0);
                acc[ot][xt] = __builtin_amdgcn_mfma_f32_16x16x32_bf16(afl[ot], bfh[xt], acc[ot][xt], 0, 0, 0);
                acc[ot][xt] = __builtin_amdgcn_mfma_f32_16x16x32_bf16(afh[ot], bfh[xt], acc[ot][xt], 0, 0, 0);
            }
    }
#pragma unroll
    for (int ot = 0; ot < 4; ++ot) {
        float4 bc = *(const float4*)(bconv + lay * DIM + ot * 16 + quad * 4);
#pragma unroll
        for (int xt = 0; xt < 4; ++xt) {
            int x = xw + xt * 16 + l16;
            float vr[4] = {acc[ot][xt][0] + bc.x, acc[ot][xt][1] + bc.y,
                           acc[ot][xt][2] + bc.z, acc[ot][xt][3] + bc.w};
            if (do_act) {
#pragma unroll
                for (int r = 0; r < 4; ++r) vr[r] = gelu_exact(vr[r]);
            }
            ushort4 uh, ul;
            split_bf16(vr[0], uh.x, ul.x);
            split_bf16(vr[1], uh.y, ul.y);
            split_bf16(vr[2], uh.z, ul.z);
            split_bf16(vr[3], uh.w, ul.w);
            size_t ho = ((size_t)(b << 14) + x) * 64 + ot * 16 + quad * 4;
            *(ushort4*)(Hh + ho) = uh;
            *(ushort4*)(Hl + ho) = ul;
        }
    }
}

// Final MLP via MFMA: gemm1 = h(16x64) @ W1(64x128) split-bf16; gelu in-reg;
// out = gemm1 @ W2 via per-lane scale + shfl-xor reduce over the f lanes.
// grid (256, 32) x 256 (4 waves; wave = 16 x).
__global__ __launch_bounds__(256) void k_mlp_mfma(
        const u16* __restrict__ Hh, const u16* __restrict__ Hl,
        const u16* __restrict__ W1h, const u16* __restrict__ W1l,
        const float* __restrict__ b1, const float* __restrict__ W2,
        const float* __restrict__ b2, float* __restrict__ out) {
    int t = threadIdx.x;
    int wave = t >> 6, lane = t & 63, quad = lane >> 4, l16 = lane & 15;
    int b = blockIdx.y;
    int x0 = blockIdx.x * 64 + wave * 16;
    bf16x8 ah[2], al[2];
#pragma unroll
    for (int ks = 0; ks < 2; ++ks) {
        size_t o = ((size_t)(b << 14) + x0 + l16) * 64 + ks * 32 + quad * 8;
        ah[ks] = *(const bf16x8*)(Hh + o);
        al[ks] = *(const bf16x8*)(Hl + o);
    }
    float vout[4] = {0.f, 0.f, 0.f, 0.f};
#pragma unroll
    for (int ft = 0; ft < 8; ++ft) {
        f32x4 acc = {};
#pragma unroll
        for (int ks = 0; ks < 2; ++ks) {
            size_t o = (size_t)(ft * 16 + l16) * 64 + ks * 32 + quad * 8;
            bf16x8 bh = *(const bf16x8*)(W1h + o);
            bf16x8 bl = *(const bf16x8*)(W1l + o);
            acc = __builtin_amdgcn_mfma_f32_16x16x32_bf16(ah[ks], bl, acc, 0, 0, 0);
            acc = __builtin_amdgcn_mfma_f32_16x16x32_bf16(al[ks], bh, acc, 0, 0, 0);
            acc = __builtin_amdgcn_mfma_f32_16x16x32_bf16(ah[ks], bh, acc, 0, 0, 0);
        }
        float bb = b1[ft * 16 + l16];
        float w2 = W2[ft * 16 + l16];
#pragma unroll
        for (int r = 0; r < 4; ++r)
            vout[r] += gelu_exact(acc[r] + bb) * w2;
    }
#pragma unroll
    for (int r = 0; r < 4; ++r) {
        float v = vout[r];
        v += __shfl_xor(v, 1);
        v += __shfl_xor(v, 2);
        v += __shfl_xor(v, 4);
        v += __shfl_xor(v, 8);
        vout[r] = v;
    }
    if (l16 == 0) {
        float bb2 = b2[0];
        float4 o4 = make_float4(vout[0] + bb2, vout[1] + bb2, vout[2] + bb2, vout[3] + bb2);
        *(float4*)(out + (size_t)b * NXX + x0 + quad * 4) = o4;
    }
}

// ---------------------------------------------------------------------------
extern "C" void kernel_launch(void* const* d_in, const int* in_sizes, int n_in,
                              void* d_out, int out_size, void* d_ws, size_t ws_size,
                              hipStream_t stream) {
    const float* x      = (const float*)d_in[0];
    const float* bases  = (const float*)d_in[1];
    const float* wbases = (const float*)d_in[2];
    const float* product= (const float*)d_in[3];
    const float* Dout   = (const float*)d_in[4];
    const float* Din    = (const float*)d_in[5];
    const float* A      = (const float*)d_in[6];
    const float* Bm     = (const float*)d_in[7];
    const float* Wsp    = (const float*)d_in[8];
    const float* Wconv  = (const float*)d_in[9];
    const float* bconv  = (const float*)d_in[10];
    const float* W0     = (const float*)d_in[11];
    const float* b0     = (const float*)d_in[12];
    const float* W1     = (const float*)d_in[13];
    const float* b1     = (const float*)d_in[14];
    const float* W2     = (const float*)d_in[15];
    const float* b2     = (const float*)d_in[16];
    float* out = (float*)d_out;

    // Workspace layout (byte offsets, all 16B-aligned):
    char* W = (char*)d_ws;
    float* Hbuf     = (float*)(W + 0);            // 1,048,576
    u16*   bases_hi = (u16*)(W + 1048576);        // 4,194,304
    u16*   bases_lo = (u16*)(W + 5242880);        // 4,194,304
    u16*   Abuf_hi  = (u16*)(W + 9437184);        //   786,432
    u16*   Abuf_lo  = (u16*)(W + 10223616);       //   786,432
    float* ybuf     = (float*)(W + 11010048);     // 1,048,576
    float* xh       = (float*)(W + 12058624);     // 1,048,576  (contiguous after ybuf)
    u16*   h_hi     = (u16*)(W + 13107200);       // 67,108,864
    u16*   h_lo     = (u16*)(W + 80216064);       // 67,108,864
    u16*   w1t_hi   = (u16*)(W + 147324928);      //    16,384
    u16*   w1t_lo   = (u16*)(W + 147341312);      //    16,384
    const size_t need = 147357696;                // < proven 154,140,672

    if (ws_size < need) {
        k_zero<<<dim3((out_size + 255) / 256), dim3(256), 0, stream>>>(out, out_size);
        return;
    }

    k_build_H<<<dim3(1024), dim3(256), 0, stream>>>(Dout, Din, product, A, Bm, Hbuf);
    k_setup_bases<<<dim3(8192), dim3(256), 0, stream>>>(bases, bases_hi, bases_lo);
    k_setup_w1t<<<dim3(32), dim3(256), 0, stream>>>(W1, w1t_hi, w1t_lo);
    k_fc0<<<dim3(256, B_SZ), dim3(64), 0, stream>>>(x, W0, b0, h_hi, h_lo);

    for (int lay = 0; lay < N_LAY; ++lay) {
        // zero ybuf + xh (contiguous, 524288 floats)
        k_zero<<<dim3(2048), dim3(256), 0, stream>>>(ybuf, 524288);
        k_spectral<<<dim3(64, B_SZ, 4), dim3(64), 0, stream>>>(h_hi, h_lo, wbases, xh);
        k_hmix<<<dim3(B_SZ, JM), dim3(256), 0, stream>>>(xh, Hbuf, Wsp, ybuf, lay);
        k_build_A<<<dim3(B_SZ), dim3(256), 0, stream>>>(ybuf, Wconv, Abuf_hi, Abuf_lo, lay);
        k_inv_conv_mfma<<<dim3(64, B_SZ), dim3(256), 0, stream>>>(
            Abuf_hi, Abuf_lo, bases_hi, bases_lo, h_hi, h_lo,
            bconv, lay, (lay < N_LAY - 1) ? 1 : 0);
    }
    k_mlp_mfma<<<dim3(256, B_SZ), dim3(256), 0, stream>>>(
        h_hi, h_lo, w1t_hi, w1t_lo, b1, W2, b2, out);
}

// Round 4
// 1053.003 us; speedup vs baseline: 3.2705x; 3.2705x over previous
//
#include <hip/hip_runtime.h>
#include <hip/hip_bf16.h>
#include <math.h>

#define B_SZ   32
#define NXX    16384
#define IN_DIM 3
#define DIM    64
#define JM     16
#define MODE   128
#define RANKK  4
#define FC_DIM 128
#define N_LAY  3

typedef __attribute__((ext_vector_type(8))) short bf16x8;
typedef __attribute__((ext_vector_type(4))) float f32x4;
typedef unsigned short u16;

__device__ __forceinline__ float gelu_exact(float v) {
    return 0.5f * v * (1.0f + erff(v * 0.70710678118654752f));
}
__device__ __forceinline__ float bf2f(u16 u) {
    return __uint_as_float((unsigned)u << 16);
}
__device__ __forceinline__ void split_bf16(float v, u16& h, u16& l) {
    __hip_bfloat16 bh = __float2bfloat16(v);
    float fh = __bfloat162float(bh);
    __hip_bfloat16 bl = __float2bfloat16(v - fh);
    h = *(u16*)&bh;
    l = *(u16*)&bl;
}

// ---------------------------------------------------------------------------
__global__ __launch_bounds__(256) void k_zero(float* __restrict__ p, int n) {
    int i = blockIdx.x * 256 + threadIdx.x;
    if (i < n) p[i] = 0.f;
}

// H[j,k,l] = D_out[j,k]*D_in[j,l]*product[k,l] + sum_r A[j,r,k]*Bm[j,r,l]
__global__ __launch_bounds__(256) void k_build_H(
        const float* __restrict__ Dout, const float* __restrict__ Din,
        const float* __restrict__ product, const float* __restrict__ A,
        const float* __restrict__ Bm, float* __restrict__ H) {
    int idx = blockIdx.x * 256 + threadIdx.x;
    int j = idx >> 14;
    int k = (idx >> 7) & 127;
    int l = idx & 127;
    float v = Dout[j * MODE + k] * Din[j * MODE + l] * product[k * MODE + l];
#pragma unroll
    for (int r = 0; r < RANKK; ++r)
        v += A[(j * RANKK + r) * MODE + k] * Bm[(j * RANKK + r) * MODE + l];
    H[idx] = v;
}

// bases (fp32 [x][k]) -> hi/lo bf16 planes, same layout.  grid 8192 x 256
// (lo may be null -> hi only)
__global__ __launch_bounds__(256) void k_setup_bases(
        const float* __restrict__ bases, u16* __restrict__ bh, u16* __restrict__ bl) {
    int i = blockIdx.x * 256 + threadIdx.x;
    u16 h, l;
    split_bf16(bases[i], h, l);
    bh[i] = h;
    if (bl) bl[i] = l;
}

// wbT[l][x] = wbases[x][l], split hi/lo.  grid (512, 4) x 256, LDS-tiled.
__global__ __launch_bounds__(256) void k_setup_wbT(
        const float* __restrict__ wb, u16* __restrict__ Th, u16* __restrict__ Tl) {
    __shared__ float tile[32][33];
    int bx = blockIdx.x, bl = blockIdx.y;
    int t = threadIdx.x;
    int i = t >> 5, jj = t & 31;
#pragma unroll
    for (int r = 0; r < 4; ++r)
        tile[i + r * 8][jj] = wb[(size_t)(bx * 32 + i + r * 8) * MODE + bl * 32 + jj];
    __syncthreads();
#pragma unroll
    for (int r = 0; r < 4; ++r) {
        int l = bl * 32 + i + r * 8;
        int x = bx * 32 + jj;
        u16 h, lo;
        split_bf16(tile[jj][i + r * 8], h, lo);
        Th[(size_t)l * NXX + x] = h;
        Tl[(size_t)l * NXX + x] = lo;
    }
}

// W1T[f*64+c] = W1[c*128+f] hi/lo.  grid 32 x 256
__global__ __launch_bounds__(256) void k_setup_w1t(
        const float* __restrict__ W1, u16* __restrict__ wh, u16* __restrict__ wl) {
    int i = blockIdx.x * 256 + threadIdx.x;
    int f = i >> 6, c = i & 63;
    u16 h, l;
    split_bf16(W1[c * FC_DIM + f], h, l);
    wh[i] = h; wl[i] = l;
}

// fc0: h[b,x,c] = sum_d x[b,x,d]*W0[d,c] + b0[c]   grid (256, 32) x 64
__global__ __launch_bounds__(64) void k_fc0(
        const float* __restrict__ x, const float* __restrict__ W0,
        const float* __restrict__ b0, u16* __restrict__ hh, u16* __restrict__ hl) {
    int lane = threadIdx.x;
    int b = blockIdx.y;
    int x0 = blockIdx.x * 64;
    float w0 = W0[0 * DIM + lane], w1 = W0[1 * DIM + lane], w2 = W0[2 * DIM + lane];
    float bb = b0[lane];
    for (int xx = 0; xx < 64; ++xx) {
        const float* xp = x + ((size_t)b * NXX + x0 + xx) * IN_DIM;
        float v = xp[0] * w0 + xp[1] * w1 + xp[2] * w2 + bb;
        u16 h, l;
        split_bf16(v, h, l);
        size_t o = ((size_t)(b << 14) + x0 + xx) * 64 + lane;
        hh[o] = h; hl[o] = l;
    }
}

// ---------------------------------------------------------------------------
// Spectral via MFMA: xh[b][c][l] += sum_x h[b][x][c] * wbases[x][l]
// A = hT (m=c, k=x) via in-register 4x4 transpose -> LDS; B = wbT[l][x] global.
// Split-bf16: acc += Ah*Bl + Al*Bh + Ah*Bh.  Split-K atomics into zeroed xh.
// grid (32 b, 16 ks) x 256 (4 waves; wave = 16c x 32l of the 64x128 output).
#define SPAD 72
__global__ __launch_bounds__(256, 2) void k_spectral_mfma(
        const u16* __restrict__ Hh, const u16* __restrict__ Hl,
        const u16* __restrict__ Wh, const u16* __restrict__ Wl,
        float* __restrict__ xh) {
    __shared__ u16 Ash[64 * SPAD];
    __shared__ u16 Asl[64 * SPAD];
    int t = threadIdx.x;
    int wave = t >> 6, lane = t & 63, quad = lane >> 4, l16 = lane & 15;
    int b = blockIdx.x;
    int x0 = blockIdx.y * 1024;
    int cq = (t & 15) * 4;      // staging: c-block (consecutive lanes -> coalesced)
    int xq = (t >> 4) * 4;      // staging: x-block
    const u16* srch = Hh + ((size_t)(b << 14) + x0 + xq) * 64 + cq;
    const u16* srcl = Hl + ((size_t)(b << 14) + x0 + xq) * 64 + cq;
    int l0 = wave * 32;
    const u16* w0h = Wh + (size_t)(l0 + l16) * NXX + x0;
    const u16* w1h = Wh + (size_t)(l0 + 16 + l16) * NXX + x0;
    const u16* w0l = Wl + (size_t)(l0 + l16) * NXX + x0;
    const u16* w1l = Wl + (size_t)(l0 + 16 + l16) * NXX + x0;
    f32x4 acc[4][2] = {};
    for (int kt = 0; kt < 1024; kt += 64) {
        __syncthreads();
        {
            const u16* s = srch + (size_t)kt * 64;
            ushort4 r0 = *(const ushort4*)(s);
            ushort4 r1 = *(const ushort4*)(s + 64);
            ushort4 r2 = *(const ushort4*)(s + 128);
            ushort4 r3 = *(const ushort4*)(s + 192);
            *(ushort4*)&Ash[(cq + 0) * SPAD + xq] = make_ushort4(r0.x, r1.x, r2.x, r3.x);
            *(ushort4*)&Ash[(cq + 1) * SPAD + xq] = make_ushort4(r0.y, r1.y, r2.y, r3.y);
            *(ushort4*)&Ash[(cq + 2) * SPAD + xq] = make_ushort4(r0.z, r1.z, r2.z, r3.z);
            *(ushort4*)&Ash[(cq + 3) * SPAD + xq] = make_ushort4(r0.w, r1.w, r2.w, r3.w);
            s = srcl + (size_t)kt * 64;
            r0 = *(const ushort4*)(s);
            r1 = *(const ushort4*)(s + 64);
            r2 = *(const ushort4*)(s + 128);
            r3 = *(const ushort4*)(s + 192);
            *(ushort4*)&Asl[(cq + 0) * SPAD + xq] = make_ushort4(r0.x, r1.x, r2.x, r3.x);
            *(ushort4*)&Asl[(cq + 1) * SPAD + xq] = make_ushort4(r0.y, r1.y, r2.y, r3.y);
            *(ushort4*)&Asl[(cq + 2) * SPAD + xq] = make_ushort4(r0.z, r1.z, r2.z, r3.z);
            *(ushort4*)&Asl[(cq + 3) * SPAD + xq] = make_ushort4(r0.w, r1.w, r2.w, r3.w);
        }
        __syncthreads();
#pragma unroll
        for (int k0 = 0; k0 < 64; k0 += 32) {
            bf16x8 afh[4], afl[4];
#pragma unroll
            for (int ct = 0; ct < 4; ++ct) {
                int ro = (ct * 16 + l16) * SPAD + k0 + quad * 8;
                afh[ct] = *(const bf16x8*)&Ash[ro];
                afl[ct] = *(const bf16x8*)&Asl[ro];
            }
            int go = kt + k0 + quad * 8;
            bf16x8 b0h = *(const bf16x8*)(w0h + go);
            bf16x8 b0l = *(const bf16x8*)(w0l + go);
            bf16x8 b1h = *(const bf16x8*)(w1h + go);
            bf16x8 b1l = *(const bf16x8*)(w1l + go);
#pragma unroll
            for (int ct = 0; ct < 4; ++ct) {
                acc[ct][0] = __builtin_amdgcn_mfma_f32_16x16x32_bf16(afh[ct], b0l, acc[ct][0], 0, 0, 0);
                acc[ct][0] = __builtin_amdgcn_mfma_f32_16x16x32_bf16(afl[ct], b0h, acc[ct][0], 0, 0, 0);
                acc[ct][0] = __builtin_amdgcn_mfma_f32_16x16x32_bf16(afh[ct], b0h, acc[ct][0], 0, 0, 0);
                acc[ct][1] = __builtin_amdgcn_mfma_f32_16x16x32_bf16(afh[ct], b1l, acc[ct][1], 0, 0, 0);
                acc[ct][1] = __builtin_amdgcn_mfma_f32_16x16x32_bf16(afl[ct], b1h, acc[ct][1], 0, 0, 0);
                acc[ct][1] = __builtin_amdgcn_mfma_f32_16x16x32_bf16(afh[ct], b1h, acc[ct][1], 0, 0, 0);
            }
        }
    }
    float* xb = xh + (size_t)(b << 6) * 128;
#pragma unroll
    for (int ct = 0; ct < 4; ++ct)
#pragma unroll
        for (int lt = 0; lt < 2; ++lt)
#pragma unroll
            for (int r = 0; r < 4; ++r)
                atomicAdd(xb + (size_t)(ct * 16 + quad * 4 + r) * 128 + l0 + lt * 16 + l16,
                          acc[ct][lt][r]);
}

// ---------------------------------------------------------------------------
// Fused H-mix + channel contraction.  grid (32, 16) x 256
__global__ __launch_bounds__(256) void k_hmix(
        const float* __restrict__ xh, const float* __restrict__ H,
        const float* __restrict__ Wsp, float* __restrict__ y, int lay) {
    __shared__ float xs[DIM][132];
    __shared__ float Ts[DIM][MODE];
    __shared__ float Ws[DIM][DIM];
    int t = threadIdx.x;
    int b = blockIdx.x;
    int j = blockIdx.y;
    const float* xb = xh + (size_t)b * DIM * MODE;
    for (int idx = t; idx < DIM * MODE; idx += 256)
        xs[idx >> 7][idx & 127] = xb[idx];
    const float* Wl = Wsp + (size_t)lay * DIM * DIM * JM + j;
    for (int idx = t; idx < DIM * DIM; idx += 256)
        Ws[idx >> 6][idx & 63] = Wl[(size_t)idx * JM];
    __syncthreads();
    {
        int k4 = (t & 31) * 4;
        int i0 = (t >> 5) * 8;
        float acc[8][4] = {};
        const float* Hbase = H + ((size_t)j * MODE + k4) * MODE;
        for (int l = 0; l < MODE; l += 4) {
            float4 hv0 = *(const float4*)(Hbase + 0 * MODE + l);
            float4 hv1 = *(const float4*)(Hbase + 1 * MODE + l);
            float4 hv2 = *(const float4*)(Hbase + 2 * MODE + l);
            float4 hv3 = *(const float4*)(Hbase + 3 * MODE + l);
#pragma unroll
            for (int ii = 0; ii < 8; ++ii) {
                float4 xv = *(const float4*)&xs[i0 + ii][l];
                acc[ii][0] += hv0.x * xv.x + hv0.y * xv.y + hv0.z * xv.z + hv0.w * xv.w;
                acc[ii][1] += hv1.x * xv.x + hv1.y * xv.y + hv1.z * xv.z + hv1.w * xv.w;
                acc[ii][2] += hv2.x * xv.x + hv2.y * xv.y + hv2.z * xv.z + hv2.w * xv.w;
                acc[ii][3] += hv3.x * xv.x + hv3.y * xv.y + hv3.z * xv.z + hv3.w * xv.w;
            }
        }
#pragma unroll
        for (int ii = 0; ii < 8; ++ii)
            *(float4*)&Ts[i0 + ii][k4] = make_float4(acc[ii][0], acc[ii][1], acc[ii][2], acc[ii][3]);
    }
    __syncthreads();
    {
        int k = t & 127;
        int o0 = (t >> 7) * 32;
        float acc2[32] = {};
        for (int i = 0; i < DIM; ++i) {
            float tv = Ts[i][k];
            const float* wr = &Ws[i][o0];
#pragma unroll
            for (int o4 = 0; o4 < 32; o4 += 4) {
                float4 wv = *(const float4*)(wr + o4);
                acc2[o4 + 0] += wv.x * tv;
                acc2[o4 + 1] += wv.y * tv;
                acc2[o4 + 2] += wv.z * tv;
                acc2[o4 + 3] += wv.w * tv;
            }
        }
        float* yp = y + ((size_t)b * DIM + o0) * MODE + k;
#pragma unroll
        for (int o = 0; o < 32; ++o)
            atomicAdd(yp + (size_t)o * MODE, acc2[o]);
    }
}

// Abuf[b][o][kk] = kk<128 ? y[b,o,kk] : Wconv[lay][o][kk-128], split hi/lo.
__global__ __launch_bounds__(256) void k_build_A(
        const float* __restrict__ y, const float* __restrict__ Wconv,
        u16* __restrict__ Ah, u16* __restrict__ Al, int lay) {
    int b = blockIdx.x;
    for (int idx = threadIdx.x; idx < DIM * 192; idx += 256) {
        int o = idx / 192, kk = idx % 192;
        float v = (kk < 128) ? y[((size_t)b * DIM + o) * MODE + kk]
                             : Wconv[(size_t)lay * DIM * DIM + o * DIM + (kk - 128)];
        u16 h, l;
        split_bf16(v, h, l);
        size_t off = ((size_t)b * DIM + o) * 192 + kk;
        Ah[off] = h; Al[off] = l;
    }
}

// Split-bf16 MFMA: h[b,o,x] = act( A(64x192) @ B(192x_xtile) + bconv )
// BLO: whether bases_lo plane exists (reduced-ws tier drops it).
// grid (64, 32) x 256 (4 waves; wave = 64 x).
template <bool BLO>
__global__ __launch_bounds__(256, 2) void k_inv_conv_mfma(
        const u16* __restrict__ Ah, const u16* __restrict__ Al,
        const u16* __restrict__ Bh, const u16* __restrict__ Bl,
        u16* __restrict__ Hh, u16* __restrict__ Hl,
        const float* __restrict__ bconv, int lay, int do_act) {
    int t = threadIdx.x;
    int wave = t >> 6, lane = t & 63, quad = lane >> 4, l16 = lane & 15;
    int b = blockIdx.y;
    int xw = blockIdx.x * 256 + wave * 64;
    f32x4 acc[4][4] = {};
#pragma unroll
    for (int ks = 0; ks < 6; ++ks) {
        int k0 = ks * 32;
        bf16x8 afh[4], afl[4], bfh[4], bfl[4];
        bool haslo = BLO || ks >= 4;
#pragma unroll
        for (int ot = 0; ot < 4; ++ot) {
            size_t ao = ((size_t)(b * 64 + ot * 16 + l16)) * 192 + k0 + quad * 8;
            afh[ot] = *(const bf16x8*)(Ah + ao);
            afl[ot] = *(const bf16x8*)(Al + ao);
        }
#pragma unroll
        for (int xt = 0; xt < 4; ++xt) {
            int x = xw + xt * 16 + l16;
            if (ks < 4) {
                size_t bo = (size_t)x * MODE + k0 + quad * 8;
                bfh[xt] = *(const bf16x8*)(Bh + bo);
                if (BLO) bfl[xt] = *(const bf16x8*)(Bl + bo);
            } else {
                size_t bo = ((size_t)(b << 14) + x) * 64 + (k0 - 128) + quad * 8;
                bfh[xt] = *(const bf16x8*)(Hh + bo);
                bfl[xt] = *(const bf16x8*)(Hl + bo);
            }
        }
#pragma unroll
        for (int ot = 0; ot < 4; ++ot)
#pragma unroll
            for (int xt = 0; xt < 4; ++xt) {
                if (haslo)
                    acc[ot][xt] = __builtin_amdgcn_mfma_f32_16x16x32_bf16(afh[ot], bfl[xt], acc[ot][xt], 0, 0, 0);
                acc[ot][xt] = __builtin_amdgcn_mfma_f32_16x16x32_bf16(afl[ot], bfh[xt], acc[ot][xt], 0, 0, 0);
                acc[ot][xt] = __builtin_amdgcn_mfma_f32_16x16x32_bf16(afh[ot], bfh[xt], acc[ot][xt], 0, 0, 0);
            }
    }
#pragma unroll
    for (int ot = 0; ot < 4; ++ot) {
        float4 bc = *(const float4*)(bconv + lay * DIM + ot * 16 + quad * 4);
#pragma unroll
        for (int xt = 0; xt < 4; ++xt) {
            int x = xw + xt * 16 + l16;
            float vr[4] = {acc[ot][xt][0] + bc.x, acc[ot][xt][1] + bc.y,
                           acc[ot][xt][2] + bc.z, acc[ot][xt][3] + bc.w};
            if (do_act) {
#pragma unroll
                for (int r = 0; r < 4; ++r) vr[r] = gelu_exact(vr[r]);
            }
            ushort4 uh, ul;
            split_bf16(vr[0], uh.x, ul.x);
            split_bf16(vr[1], uh.y, ul.y);
            split_bf16(vr[2], uh.z, ul.z);
            split_bf16(vr[3], uh.w, ul.w);
            size_t ho = ((size_t)(b << 14) + x) * 64 + ot * 16 + quad * 4;
            *(ushort4*)(Hh + ho) = uh;
            *(ushort4*)(Hl + ho) = ul;
        }
    }
}

// Final MLP via MFMA.  grid (256, 32) x 256 (4 waves; wave = 16 x).
__global__ __launch_bounds__(256) void k_mlp_mfma(
        const u16* __restrict__ Hh, const u16* __restrict__ Hl,
        const u16* __restrict__ W1h, const u16* __restrict__ W1l,
        const float* __restrict__ b1, const float* __restrict__ W2,
        const float* __restrict__ b2, float* __restrict__ out) {
    int t = threadIdx.x;
    int wave = t >> 6, lane = t & 63, quad = lane >> 4, l16 = lane & 15;
    int b = blockIdx.y;
    int x0 = blockIdx.x * 64 + wave * 16;
    bf16x8 ah[2], al[2];
#pragma unroll
    for (int ks = 0; ks < 2; ++ks) {
        size_t o = ((size_t)(b << 14) + x0 + l16) * 64 + ks * 32 + quad * 8;
        ah[ks] = *(const bf16x8*)(Hh + o);
        al[ks] = *(const bf16x8*)(Hl + o);
    }
    float vout[4] = {0.f, 0.f, 0.f, 0.f};
#pragma unroll
    for (int ft = 0; ft < 8; ++ft) {
        f32x4 acc = {};
#pragma unroll
        for (int ks = 0; ks < 2; ++ks) {
            size_t o = (size_t)(ft * 16 + l16) * 64 + ks * 32 + quad * 8;
            bf16x8 bh = *(const bf16x8*)(W1h + o);
            bf16x8 bl = *(const bf16x8*)(W1l + o);
            acc = __builtin_amdgcn_mfma_f32_16x16x32_bf16(ah[ks], bl, acc, 0, 0, 0);
            acc = __builtin_amdgcn_mfma_f32_16x16x32_bf16(al[ks], bh, acc, 0, 0, 0);
            acc = __builtin_amdgcn_mfma_f32_16x16x32_bf16(ah[ks], bh, acc, 0, 0, 0);
        }
        float bb = b1[ft * 16 + l16];
        float w2 = W2[ft * 16 + l16];
#pragma unroll
        for (int r = 0; r < 4; ++r)
            vout[r] += gelu_exact(acc[r] + bb) * w2;
    }
#pragma unroll
    for (int r = 0; r < 4; ++r) {
        float v = vout[r];
        v += __shfl_xor(v, 1);
        v += __shfl_xor(v, 2);
        v += __shfl_xor(v, 4);
        v += __shfl_xor(v, 8);
        vout[r] = v;
    }
    if (l16 == 0) {
        float bb2 = b2[0];
        float4 o4 = make_float4(vout[0] + bb2, vout[1] + bb2, vout[2] + bb2, vout[3] + bb2);
        *(float4*)(out + (size_t)b * NXX + x0 + quad * 4) = o4;
    }
}

// ---------------------------------------------------------------------------
extern "C" void kernel_launch(void* const* d_in, const int* in_sizes, int n_in,
                              void* d_out, int out_size, void* d_ws, size_t ws_size,
                              hipStream_t stream) {
    const float* x      = (const float*)d_in[0];
    const float* bases  = (const float*)d_in[1];
    const float* wbases = (const float*)d_in[2];
    const float* product= (const float*)d_in[3];
    const float* Dout   = (const float*)d_in[4];
    const float* Din    = (const float*)d_in[5];
    const float* A      = (const float*)d_in[6];
    const float* Bm     = (const float*)d_in[7];
    const float* Wsp    = (const float*)d_in[8];
    const float* Wconv  = (const float*)d_in[9];
    const float* bconv  = (const float*)d_in[10];
    const float* W0     = (const float*)d_in[11];
    const float* b0     = (const float*)d_in[12];
    const float* W1     = (const float*)d_in[13];
    const float* b1     = (const float*)d_in[14];
    const float* W2     = (const float*)d_in[15];
    const float* b2     = (const float*)d_in[16];
    float* out = (float*)d_out;

    const size_t need_full    = 155746304;   // all buffers incl. bases_lo
    const size_t need_reduced = 151552000;   // drops bases_lo (4 MB)
    bool full = ws_size >= need_full;
    if (!full && ws_size < need_reduced) {
        k_zero<<<dim3((out_size + 255) / 256), dim3(256), 0, stream>>>(out, out_size);
        return;
    }

    char* W = (char*)d_ws;
    size_t off = 0;
    auto alloc = [&](size_t bytes) { void* p = W + off; off += bytes; return p; };
    float* Hbuf     = (float*)alloc(1048576);
    u16*   bases_hi = (u16*)alloc(4194304);
    u16*   bases_lo = full ? (u16*)alloc(4194304) : nullptr;
    u16*   wbT_hi   = (u16*)alloc(4194304);
    u16*   wbT_lo   = (u16*)alloc(4194304);
    u16*   Abuf_hi  = (u16*)alloc(786432);
    u16*   Abuf_lo  = (u16*)alloc(786432);
    float* ybuf     = (float*)alloc(1048576);
    float* xh       = (float*)alloc(1048576);   // must follow ybuf (joint zeroing)
    u16*   h_hi     = (u16*)alloc(67108864);
    u16*   h_lo     = (u16*)alloc(67108864);
    u16*   w1t_hi   = (u16*)alloc(16384);
    u16*   w1t_lo   = (u16*)alloc(16384);

    k_build_H<<<dim3(1024), dim3(256), 0, stream>>>(Dout, Din, product, A, Bm, Hbuf);
    k_setup_bases<<<dim3(8192), dim3(256), 0, stream>>>(bases, bases_hi, bases_lo);
    k_setup_wbT<<<dim3(512, 4), dim3(256), 0, stream>>>(wbases, wbT_hi, wbT_lo);
    k_setup_w1t<<<dim3(32), dim3(256), 0, stream>>>(W1, w1t_hi, w1t_lo);
    k_fc0<<<dim3(256, B_SZ), dim3(64), 0, stream>>>(x, W0, b0, h_hi, h_lo);

    for (int lay = 0; lay < N_LAY; ++lay) {
        k_zero<<<dim3(2048), dim3(256), 0, stream>>>(ybuf, 524288);  // ybuf + xh
        k_spectral_mfma<<<dim3(B_SZ, 16), dim3(256), 0, stream>>>(
            h_hi, h_lo, wbT_hi, wbT_lo, xh);
        k_hmix<<<dim3(B_SZ, JM), dim3(256), 0, stream>>>(xh, Hbuf, Wsp, ybuf, lay);
        k_build_A<<<dim3(B_SZ), dim3(256), 0, stream>>>(ybuf, Wconv, Abuf_hi, Abuf_lo, lay);
        if (full)
            k_inv_conv_mfma<true><<<dim3(64, B_SZ), dim3(256), 0, stream>>>(
                Abuf_hi, Abuf_lo, bases_hi, bases_lo, h_hi, h_lo,
                bconv, lay, (lay < N_LAY - 1) ? 1 : 0);
        else
            k_inv_conv_mfma<false><<<dim3(64, B_SZ), dim3(256), 0, stream>>>(
                Abuf_hi, Abuf_lo, bases_hi, bases_hi, h_hi, h_lo,
                bconv, lay, (lay < N_LAY - 1) ? 1 : 0);
    }
    k_mlp_mfma<<<dim3(256, B_SZ), dim3(256), 0, stream>>>(
        h_hi, h_lo, w1t_hi, w1t_lo, b1, W2, b2, out);
}

// Round 5
// 918.423 us; speedup vs baseline: 3.7498x; 1.1465x over previous
//
#include <hip/hip_runtime.h>
#include <hip/hip_bf16.h>
#include <math.h>

#define B_SZ   32
#define NXX    16384
#define IN_DIM 3
#define DIM    64
#define JM     16
#define MODE   128
#define RANKK  4
#define FC_DIM 128
#define N_LAY  3

typedef __attribute__((ext_vector_type(8))) short bf16x8;
typedef __attribute__((ext_vector_type(4))) float f32x4;
typedef unsigned short u16;

__device__ __forceinline__ float gelu_exact(float v) {
    return 0.5f * v * (1.0f + erff(v * 0.70710678118654752f));
}
__device__ __forceinline__ float bf2f(u16 u) {
    return __uint_as_float((unsigned)u << 16);
}
__device__ __forceinline__ void split_bf16(float v, u16& h, u16& l) {
    __hip_bfloat16 bh = __float2bfloat16(v);
    float fh = __bfloat162float(bh);
    __hip_bfloat16 bl = __float2bfloat16(v - fh);
    h = *(u16*)&bh;
    l = *(u16*)&bl;
}

// ---------------------------------------------------------------------------
__global__ __launch_bounds__(256) void k_zero(float* __restrict__ p, int n) {
    int i = blockIdx.x * 256 + threadIdx.x;
    if (i < n) p[i] = 0.f;
}

// H[j,k,l] = D_out[j,k]*D_in[j,l]*product[k,l] + sum_r A[j,r,k]*Bm[j,r,l]
__global__ __launch_bounds__(256) void k_build_H(
        const float* __restrict__ Dout, const float* __restrict__ Din,
        const float* __restrict__ product, const float* __restrict__ A,
        const float* __restrict__ Bm, float* __restrict__ H) {
    int idx = blockIdx.x * 256 + threadIdx.x;
    int j = idx >> 14;
    int k = (idx >> 7) & 127;
    int l = idx & 127;
    float v = Dout[j * MODE + k] * Din[j * MODE + l] * product[k * MODE + l];
#pragma unroll
    for (int r = 0; r < RANKK; ++r)
        v += A[(j * RANKK + r) * MODE + k] * Bm[(j * RANKK + r) * MODE + l];
    H[idx] = v;
}

// bases (fp32 [x][k]) -> FRAG-MAJOR hi/lo planes:
//   Bf[(k>>3)*131072 + x*8 + (k&7)]  (so a B-frag load is 16 consecutive lanes
//   reading 16 consecutive 16B chunks).  grid 8192 x 256.  (lo may be null)
__global__ __launch_bounds__(256) void k_setup_bases(
        const float* __restrict__ bases, u16* __restrict__ bh, u16* __restrict__ bl) {
    int idx = blockIdx.x * 256 + threadIdx.x;
    int x = idx >> 7, k = idx & 127;
    u16 h, l;
    split_bf16(bases[idx], h, l);
    size_t off = (size_t)(k >> 3) * 131072 + (size_t)x * 8 + (k & 7);
    bh[off] = h;
    if (bl) bl[off] = l;
}

// wbT[l][x] = wbases[x][l], split hi/lo.  grid (512, 4) x 256, LDS-tiled.
__global__ __launch_bounds__(256) void k_setup_wbT(
        const float* __restrict__ wb, u16* __restrict__ Th, u16* __restrict__ Tl) {
    __shared__ float tile[32][33];
    int bx = blockIdx.x, bl = blockIdx.y;
    int t = threadIdx.x;
    int i = t >> 5, jj = t & 31;
#pragma unroll
    for (int r = 0; r < 4; ++r)
        tile[i + r * 8][jj] = wb[(size_t)(bx * 32 + i + r * 8) * MODE + bl * 32 + jj];
    __syncthreads();
#pragma unroll
    for (int r = 0; r < 4; ++r) {
        int l = bl * 32 + i + r * 8;
        int x = bx * 32 + jj;
        u16 h, lo;
        split_bf16(tile[jj][i + r * 8], h, lo);
        Th[(size_t)l * NXX + x] = h;
        Tl[(size_t)l * NXX + x] = lo;
    }
}

// W1T[f*64+c] = W1[c*128+f] hi/lo.  grid 32 x 256
__global__ __launch_bounds__(256) void k_setup_w1t(
        const float* __restrict__ W1, u16* __restrict__ wh, u16* __restrict__ wl) {
    int i = blockIdx.x * 256 + threadIdx.x;
    int f = i >> 6, c = i & 63;
    u16 h, l;
    split_bf16(W1[c * FC_DIM + f], h, l);
    wh[i] = h; wl[i] = l;
}

// fc0: h[b,x,c] = sum_d x[b,x,d]*W0[d,c] + b0[c]   grid (256, 32) x 64
__global__ __launch_bounds__(64) void k_fc0(
        const float* __restrict__ x, const float* __restrict__ W0,
        const float* __restrict__ b0, u16* __restrict__ hh, u16* __restrict__ hl) {
    int lane = threadIdx.x;
    int b = blockIdx.y;
    int x0 = blockIdx.x * 64;
    float w0 = W0[0 * DIM + lane], w1 = W0[1 * DIM + lane], w2 = W0[2 * DIM + lane];
    float bb = b0[lane];
    for (int xx = 0; xx < 64; ++xx) {
        const float* xp = x + ((size_t)b * NXX + x0 + xx) * IN_DIM;
        float v = xp[0] * w0 + xp[1] * w1 + xp[2] * w2 + bb;
        u16 h, l;
        split_bf16(v, h, l);
        size_t o = ((size_t)(b << 14) + x0 + xx) * 64 + lane;
        hh[o] = h; hl[o] = l;
    }
}

// ---------------------------------------------------------------------------
// Spectral via MFMA: xh[b][c][l] += sum_x h[b][x][c] * wbases[x][l]
// A = hT via in-register 4x4 transpose -> LDS with ROTATION SWIZZLE
//   col(c, x) = (x + 8*((c>>2)&7)) & 63    (kills the 16-way write conflicts:
//   rows 4j at 16B-aligned stride are structurally 16-way without it)
// grid (32 b, 16 ks) x 256 (4 waves; wave = 16c x 32l).
#define SPAD 72
__global__ __launch_bounds__(256, 2) void k_spectral_mfma(
        const u16* __restrict__ Hh, const u16* __restrict__ Hl,
        const u16* __restrict__ Wh, const u16* __restrict__ Wl,
        float* __restrict__ xh) {
    __shared__ u16 Ash[64 * SPAD];
    __shared__ u16 Asl[64 * SPAD];
    int t = threadIdx.x;
    int wave = t >> 6, lane = t & 63, quad = lane >> 4, l16 = lane & 15;
    int b = blockIdx.x;
    int x0 = blockIdx.y * 1024;
    int cq = (t & 15) * 4;      // staging: c-block (consecutive lanes -> coalesced)
    int xq = (t >> 4) * 4;      // staging: x-block
    int colw = (xq + ((t & 7) << 3)) & 63;   // rotated column for writes
    const u16* srch = Hh + ((size_t)(b << 14) + x0 + xq) * 64 + cq;
    const u16* srcl = Hl + ((size_t)(b << 14) + x0 + xq) * 64 + cq;
    int l0 = wave * 32;
    const u16* w0h = Wh + (size_t)(l0 + l16) * NXX + x0;
    const u16* w1h = Wh + (size_t)(l0 + 16 + l16) * NXX + x0;
    const u16* w0l = Wl + (size_t)(l0 + l16) * NXX + x0;
    const u16* w1l = Wl + (size_t)(l0 + 16 + l16) * NXX + x0;
    f32x4 acc[4][2] = {};
    for (int kt = 0; kt < 1024; kt += 64) {
        __syncthreads();
        {
            const u16* s = srch + (size_t)kt * 64;
            ushort4 r0 = *(const ushort4*)(s);
            ushort4 r1 = *(const ushort4*)(s + 64);
            ushort4 r2 = *(const ushort4*)(s + 128);
            ushort4 r3 = *(const ushort4*)(s + 192);
            *(ushort4*)&Ash[(cq + 0) * SPAD + colw] = make_ushort4(r0.x, r1.x, r2.x, r3.x);
            *(ushort4*)&Ash[(cq + 1) * SPAD + colw] = make_ushort4(r0.y, r1.y, r2.y, r3.y);
            *(ushort4*)&Ash[(cq + 2) * SPAD + colw] = make_ushort4(r0.z, r1.z, r2.z, r3.z);
            *(ushort4*)&Ash[(cq + 3) * SPAD + colw] = make_ushort4(r0.w, r1.w, r2.w, r3.w);
            s = srcl + (size_t)kt * 64;
            r0 = *(const ushort4*)(s);
            r1 = *(const ushort4*)(s + 64);
            r2 = *(const ushort4*)(s + 128);
            r3 = *(const ushort4*)(s + 192);
            *(ushort4*)&Asl[(cq + 0) * SPAD + colw] = make_ushort4(r0.x, r1.x, r2.x, r3.x);
            *(ushort4*)&Asl[(cq + 1) * SPAD + colw] = make_ushort4(r0.y, r1.y, r2.y, r3.y);
            *(ushort4*)&Asl[(cq + 2) * SPAD + colw] = make_ushort4(r0.z, r1.z, r2.z, r3.z);
            *(ushort4*)&Asl[(cq + 3) * SPAD + colw] = make_ushort4(r0.w, r1.w, r2.w, r3.w);
        }
        __syncthreads();
#pragma unroll
        for (int k0 = 0; k0 < 64; k0 += 32) {
            bf16x8 afh[4], afl[4];
#pragma unroll
            for (int ct = 0; ct < 4; ++ct) {
                int rr = ct * 16 + l16;
                int ro = rr * SPAD + (((k0 + quad * 8) + (((rr >> 2) & 7) << 3)) & 63);
                afh[ct] = *(const bf16x8*)&Ash[ro];
                afl[ct] = *(const bf16x8*)&Asl[ro];
            }
            int go = kt + k0 + quad * 8;
            bf16x8 b0h = *(const bf16x8*)(w0h + go);
            bf16x8 b0l = *(const bf16x8*)(w0l + go);
            bf16x8 b1h = *(const bf16x8*)(w1h + go);
            bf16x8 b1l = *(const bf16x8*)(w1l + go);
#pragma unroll
            for (int ct = 0; ct < 4; ++ct) {
                acc[ct][0] = __builtin_amdgcn_mfma_f32_16x16x32_bf16(afh[ct], b0l, acc[ct][0], 0, 0, 0);
                acc[ct][0] = __builtin_amdgcn_mfma_f32_16x16x32_bf16(afl[ct], b0h, acc[ct][0], 0, 0, 0);
                acc[ct][0] = __builtin_amdgcn_mfma_f32_16x16x32_bf16(afh[ct], b0h, acc[ct][0], 0, 0, 0);
                acc[ct][1] = __builtin_amdgcn_mfma_f32_16x16x32_bf16(afh[ct], b1l, acc[ct][1], 0, 0, 0);
                acc[ct][1] = __builtin_amdgcn_mfma_f32_16x16x32_bf16(afl[ct], b1h, acc[ct][1], 0, 0, 0);
                acc[ct][1] = __builtin_amdgcn_mfma_f32_16x16x32_bf16(afh[ct], b1h, acc[ct][1], 0, 0, 0);
            }
        }
    }
    float* xb = xh + (size_t)(b << 6) * 128;
#pragma unroll
    for (int ct = 0; ct < 4; ++ct)
#pragma unroll
        for (int lt = 0; lt < 2; ++lt)
#pragma unroll
            for (int r = 0; r < 4; ++r)
                atomicAdd(xb + (size_t)(ct * 16 + quad * 4 + r) * 128 + l0 + lt * 16 + l16,
                          acc[ct][lt][r]);
}

// ---------------------------------------------------------------------------
// Fused H-mix + channel contraction.  grid (32, 16) x 256
__global__ __launch_bounds__(256) void k_hmix(
        const float* __restrict__ xh, const float* __restrict__ H,
        const float* __restrict__ Wsp, float* __restrict__ y, int lay) {
    __shared__ float xs[DIM][132];
    __shared__ float Ts[DIM][MODE];
    __shared__ float Ws[DIM][DIM];
    int t = threadIdx.x;
    int b = blockIdx.x;
    int j = blockIdx.y;
    const float* xb = xh + (size_t)b * DIM * MODE;
    for (int idx = t; idx < DIM * MODE; idx += 256)
        xs[idx >> 7][idx & 127] = xb[idx];
    const float* Wl = Wsp + (size_t)lay * DIM * DIM * JM + j;
    for (int idx = t; idx < DIM * DIM; idx += 256)
        Ws[idx >> 6][idx & 63] = Wl[(size_t)idx * JM];
    __syncthreads();
    {
        int k4 = (t & 31) * 4;
        int i0 = (t >> 5) * 8;
        float acc[8][4] = {};
        const float* Hbase = H + ((size_t)j * MODE + k4) * MODE;
        for (int l = 0; l < MODE; l += 4) {
            float4 hv0 = *(const float4*)(Hbase + 0 * MODE + l);
            float4 hv1 = *(const float4*)(Hbase + 1 * MODE + l);
            float4 hv2 = *(const float4*)(Hbase + 2 * MODE + l);
            float4 hv3 = *(const float4*)(Hbase + 3 * MODE + l);
#pragma unroll
            for (int ii = 0; ii < 8; ++ii) {
                float4 xv = *(const float4*)&xs[i0 + ii][l];
                acc[ii][0] += hv0.x * xv.x + hv0.y * xv.y + hv0.z * xv.z + hv0.w * xv.w;
                acc[ii][1] += hv1.x * xv.x + hv1.y * xv.y + hv1.z * xv.z + hv1.w * xv.w;
                acc[ii][2] += hv2.x * xv.x + hv2.y * xv.y + hv2.z * xv.z + hv2.w * xv.w;
                acc[ii][3] += hv3.x * xv.x + hv3.y * xv.y + hv3.z * xv.z + hv3.w * xv.w;
            }
        }
#pragma unroll
        for (int ii = 0; ii < 8; ++ii)
            *(float4*)&Ts[i0 + ii][k4] = make_float4(acc[ii][0], acc[ii][1], acc[ii][2], acc[ii][3]);
    }
    __syncthreads();
    {
        int k = t & 127;
        int o0 = (t >> 7) * 32;
        float acc2[32] = {};
        for (int i = 0; i < DIM; ++i) {
            float tv = Ts[i][k];
            const float* wr = &Ws[i][o0];
#pragma unroll
            for (int o4 = 0; o4 < 32; o4 += 4) {
                float4 wv = *(const float4*)(wr + o4);
                acc2[o4 + 0] += wv.x * tv;
                acc2[o4 + 1] += wv.y * tv;
                acc2[o4 + 2] += wv.z * tv;
                acc2[o4 + 3] += wv.w * tv;
            }
        }
        float* yp = y + ((size_t)b * DIM + o0) * MODE + k;
#pragma unroll
        for (int o = 0; o < 32; ++o)
            atomicAdd(yp + (size_t)o * MODE, acc2[o]);
    }
}

// A buffer in FRAG-MAJOR layout: per b, idx = ((ks*4+ot)*4+quad)*16*8 + l16*8 + i
// maps (o = ot*16+l16, k = ks*32+quad*8+i);  k<128 -> y, else Wconv.
// grid (32) x 256
__global__ __launch_bounds__(256) void k_build_A(
        const float* __restrict__ y, const float* __restrict__ Wconv,
        u16* __restrict__ Ah, u16* __restrict__ Al, int lay) {
    int b = blockIdx.x;
    for (int idx = threadIdx.x; idx < 12288; idx += 256) {
        int i = idx & 7, l16 = (idx >> 3) & 15, quad = (idx >> 7) & 3,
            ot = (idx >> 9) & 3, ks = idx >> 11;
        int o = ot * 16 + l16;
        int k = ks * 32 + quad * 8 + i;
        float v = (k < 128) ? y[((size_t)b * DIM + o) * MODE + k]
                            : Wconv[(size_t)lay * DIM * DIM + o * DIM + (k - 128)];
        u16 h, l;
        split_bf16(v, h, l);
        size_t off = (size_t)b * 12288 + idx;
        Ah[off] = h; Al[off] = l;
    }
}

// ---------------------------------------------------------------------------
// inv_conv v2: h[b,o,x] = act( A(64x192) @ B(192 x 128x-tile) + bconv )
//  - A-frags & bases-B-frags: frag-major global layouts -> coalesced 16B/lane
//  - h conv-part: staged via LDS (coalesced ushort8 in, 2-way frag reads out)
//  - C: through LDS (reusing the h tile) -> full-row coalesced stores
// grid (32 b, 128 xt) x 256 (4 waves; wave = 64o x 32x).  In-place on h.
#define CPAD 72
template <bool BLO>
__global__ __launch_bounds__(256, 2) void k_inv_conv_mfma(
        const u16* __restrict__ Afh, const u16* __restrict__ Afl,
        const u16* __restrict__ Bfh, const u16* __restrict__ Bfl,
        u16* __restrict__ Hh, u16* __restrict__ Hl,
        const float* __restrict__ bconv, int lay, int do_act) {
    __shared__ u16 hsh[128 * CPAD];
    __shared__ u16 hsl[128 * CPAD];
    int t = threadIdx.x;
    int wave = t >> 6, lane = t & 63, quad = lane >> 4, l16 = lane & 15;
    int b = blockIdx.x;
    int x0 = blockIdx.y * 128;
    // stage h tile [128 x][64 c] -> LDS (coalesced 16B chunks)
#pragma unroll
    for (int it = 0; it < 4; ++it) {
        int idx = it * 256 + t;
        int row = idx >> 3, c8 = (idx & 7) * 8;
        size_t src = ((size_t)(b << 14) + x0 + row) * 64 + c8;
        *(bf16x8*)&hsh[row * CPAD + c8] = *(const bf16x8*)(Hh + src);
        *(bf16x8*)&hsl[row * CPAD + c8] = *(const bf16x8*)(Hl + src);
    }
    __syncthreads();

    int xw = wave * 32;
    const u16* afb_h = Afh + (size_t)b * 12288;
    const u16* afb_l = Afl + (size_t)b * 12288;
    f32x4 acc[4][2] = {};
#pragma unroll
    for (int ks = 0; ks < 6; ++ks) {
        bf16x8 afh[4], afl[4], bfh[2], bfl[2];
#pragma unroll
        for (int ot = 0; ot < 4; ++ot) {
            size_t ao = (size_t)(((ks * 4 + ot) * 4 + quad) * 16 + l16) * 8;
            afh[ot] = *(const bf16x8*)(afb_h + ao);
            afl[ot] = *(const bf16x8*)(afb_l + ao);
        }
        bool haslo = BLO || ks >= 4;
#pragma unroll
        for (int x2 = 0; x2 < 2; ++x2) {
            int xl = xw + x2 * 16 + l16;
            if (ks < 4) {
                size_t bo = (size_t)((ks * 4 + quad) * 16384 + x0 + xl) * 8;
                bfh[x2] = *(const bf16x8*)(Bfh + bo);
                if (BLO) bfl[x2] = *(const bf16x8*)(Bfl + bo);
            } else {
                int ko = (ks - 4) * 32 + quad * 8;
                bfh[x2] = *(const bf16x8*)&hsh[xl * CPAD + ko];
                bfl[x2] = *(const bf16x8*)&hsl[xl * CPAD + ko];
            }
        }
#pragma unroll
        for (int ot = 0; ot < 4; ++ot)
#pragma unroll
            for (int x2 = 0; x2 < 2; ++x2) {
                if (haslo)
                    acc[ot][x2] = __builtin_amdgcn_mfma_f32_16x16x32_bf16(afh[ot], bfl[x2], acc[ot][x2], 0, 0, 0);
                acc[ot][x2] = __builtin_amdgcn_mfma_f32_16x16x32_bf16(afl[ot], bfh[x2], acc[ot][x2], 0, 0, 0);
                acc[ot][x2] = __builtin_amdgcn_mfma_f32_16x16x32_bf16(afh[ot], bfh[x2], acc[ot][x2], 0, 0, 0);
            }
    }
    __syncthreads();   // all LDS h reads done -> reuse hsh/hsl for C staging

#pragma unroll
    for (int ot = 0; ot < 4; ++ot) {
        float4 bc = *(const float4*)(bconv + lay * DIM + ot * 16 + quad * 4);
#pragma unroll
        for (int x2 = 0; x2 < 2; ++x2) {
            int xl = xw + x2 * 16 + l16;
            float vr[4] = {acc[ot][x2][0] + bc.x, acc[ot][x2][1] + bc.y,
                           acc[ot][x2][2] + bc.z, acc[ot][x2][3] + bc.w};
            if (do_act) {
#pragma unroll
                for (int r = 0; r < 4; ++r) vr[r] = gelu_exact(vr[r]);
            }
            ushort4 uh, ul;
            split_bf16(vr[0], uh.x, ul.x);
            split_bf16(vr[1], uh.y, ul.y);
            split_bf16(vr[2], uh.z, ul.z);
            split_bf16(vr[3], uh.w, ul.w);
            *(ushort4*)&hsh[xl * CPAD + ot * 16 + quad * 4] = uh;
            *(ushort4*)&hsl[xl * CPAD + ot * 16 + quad * 4] = ul;
        }
    }
    __syncthreads();
#pragma unroll
    for (int it = 0; it < 4; ++it) {
        int idx = it * 256 + t;
        int row = idx >> 3, c8 = (idx & 7) * 8;
        size_t dst = ((size_t)(b << 14) + x0 + row) * 64 + c8;
        *(bf16x8*)(Hh + dst) = *(const bf16x8*)&hsh[row * CPAD + c8];
        *(bf16x8*)(Hl + dst) = *(const bf16x8*)&hsl[row * CPAD + c8];
    }
}

// Final MLP via MFMA.  grid (256, 32) x 256 (4 waves; wave = 16 x).
__global__ __launch_bounds__(256) void k_mlp_mfma(
        const u16* __restrict__ Hh, const u16* __restrict__ Hl,
        const u16* __restrict__ W1h, const u16* __restrict__ W1l,
        const float* __restrict__ b1, const float* __restrict__ W2,
        const float* __restrict__ b2, float* __restrict__ out) {
    int t = threadIdx.x;
    int wave = t >> 6, lane = t & 63, quad = lane >> 4, l16 = lane & 15;
    int b = blockIdx.y;
    int x0 = blockIdx.x * 64 + wave * 16;
    bf16x8 ah[2], al[2];
#pragma unroll
    for (int ks = 0; ks < 2; ++ks) {
        size_t o = ((size_t)(b << 14) + x0 + l16) * 64 + ks * 32 + quad * 8;
        ah[ks] = *(const bf16x8*)(Hh + o);
        al[ks] = *(const bf16x8*)(Hl + o);
    }
    float vout[4] = {0.f, 0.f, 0.f, 0.f};
#pragma unroll
    for (int ft = 0; ft < 8; ++ft) {
        f32x4 acc = {};
#pragma unroll
        for (int ks = 0; ks < 2; ++ks) {
            size_t o = (size_t)(ft * 16 + l16) * 64 + ks * 32 + quad * 8;
            bf16x8 bh = *(const bf16x8*)(W1h + o);
            bf16x8 bl = *(const bf16x8*)(W1l + o);
            acc = __builtin_amdgcn_mfma_f32_16x16x32_bf16(ah[ks], bl, acc, 0, 0, 0);
            acc = __builtin_amdgcn_mfma_f32_16x16x32_bf16(al[ks], bh, acc, 0, 0, 0);
            acc = __builtin_amdgcn_mfma_f32_16x16x32_bf16(ah[ks], bh, acc, 0, 0, 0);
        }
        float bb = b1[ft * 16 + l16];
        float w2 = W2[ft * 16 + l16];
#pragma unroll
        for (int r = 0; r < 4; ++r)
            vout[r] += gelu_exact(acc[r] + bb) * w2;
    }
#pragma unroll
    for (int r = 0; r < 4; ++r) {
        float v = vout[r];
        v += __shfl_xor(v, 1);
        v += __shfl_xor(v, 2);
        v += __shfl_xor(v, 4);
        v += __shfl_xor(v, 8);
        vout[r] = v;
    }
    if (l16 == 0) {
        float bb2 = b2[0];
        float4 o4 = make_float4(vout[0] + bb2, vout[1] + bb2, vout[2] + bb2, vout[3] + bb2);
        *(float4*)(out + (size_t)b * NXX + x0 + quad * 4) = o4;
    }
}

// ---------------------------------------------------------------------------
extern "C" void kernel_launch(void* const* d_in, const int* in_sizes, int n_in,
                              void* d_out, int out_size, void* d_ws, size_t ws_size,
                              hipStream_t stream) {
    const float* x      = (const float*)d_in[0];
    const float* bases  = (const float*)d_in[1];
    const float* wbases = (const float*)d_in[2];
    const float* product= (const float*)d_in[3];
    const float* Dout   = (const float*)d_in[4];
    const float* Din    = (const float*)d_in[5];
    const float* A      = (const float*)d_in[6];
    const float* Bm     = (const float*)d_in[7];
    const float* Wsp    = (const float*)d_in[8];
    const float* Wconv  = (const float*)d_in[9];
    const float* bconv  = (const float*)d_in[10];
    const float* W0     = (const float*)d_in[11];
    const float* b0     = (const float*)d_in[12];
    const float* W1     = (const float*)d_in[13];
    const float* b1     = (const float*)d_in[14];
    const float* W2     = (const float*)d_in[15];
    const float* b2     = (const float*)d_in[16];
    float* out = (float*)d_out;

    const size_t need_full    = 155746304;   // all buffers incl. bases_lo
    const size_t need_reduced = 151552000;   // drops bases_lo (4 MB)
    bool full = ws_size >= need_full;
    if (!full && ws_size < need_reduced) {
        k_zero<<<dim3((out_size + 255) / 256), dim3(256), 0, stream>>>(out, out_size);
        return;
    }

    char* W = (char*)d_ws;
    size_t off = 0;
    auto alloc = [&](size_t bytes) { void* p = W + off; off += bytes; return p; };
    float* Hbuf     = (float*)alloc(1048576);
    u16*   bases_hi = (u16*)alloc(4194304);
    u16*   bases_lo = full ? (u16*)alloc(4194304) : nullptr;
    u16*   wbT_hi   = (u16*)alloc(4194304);
    u16*   wbT_lo   = (u16*)alloc(4194304);
    u16*   Abuf_hi  = (u16*)alloc(786432);
    u16*   Abuf_lo  = (u16*)alloc(786432);
    float* ybuf     = (float*)alloc(1048576);
    float* xh       = (float*)alloc(1048576);   // must follow ybuf (joint zeroing)
    u16*   h_hi     = (u16*)alloc(67108864);
    u16*   h_lo     = (u16*)alloc(67108864);
    u16*   w1t_hi   = (u16*)alloc(16384);
    u16*   w1t_lo   = (u16*)alloc(16384);

    k_build_H<<<dim3(1024), dim3(256), 0, stream>>>(Dout, Din, product, A, Bm, Hbuf);
    k_setup_bases<<<dim3(8192), dim3(256), 0, stream>>>(bases, bases_hi, bases_lo);
    k_setup_wbT<<<dim3(512, 4), dim3(256), 0, stream>>>(wbases, wbT_hi, wbT_lo);
    k_setup_w1t<<<dim3(32), dim3(256), 0, stream>>>(W1, w1t_hi, w1t_lo);
    k_fc0<<<dim3(256, B_SZ), dim3(64), 0, stream>>>(x, W0, b0, h_hi, h_lo);

    for (int lay = 0; lay < N_LAY; ++lay) {
        k_zero<<<dim3(2048), dim3(256), 0, stream>>>(ybuf, 524288);  // ybuf + xh
        k_spectral_mfma<<<dim3(B_SZ, 16), dim3(256), 0, stream>>>(
            h_hi, h_lo, wbT_hi, wbT_lo, xh);
        k_hmix<<<dim3(B_SZ, JM), dim3(256), 0, stream>>>(xh, Hbuf, Wsp, ybuf, lay);
        k_build_A<<<dim3(B_SZ), dim3(256), 0, stream>>>(ybuf, Wconv, Abuf_hi, Abuf_lo, lay);
        if (full)
            k_inv_conv_mfma<true><<<dim3(B_SZ, 128), dim3(256), 0, stream>>>(
                Abuf_hi, Abuf_lo, bases_hi, bases_lo, h_hi, h_lo,
                bconv, lay, (lay < N_LAY - 1) ? 1 : 0);
        else
            k_inv_conv_mfma<false><<<dim3(B_SZ, 128), dim3(256), 0, stream>>>(
                Abuf_hi, Abuf_lo, bases_hi, bases_hi, h_hi, h_lo,
                bconv, lay, (lay < N_LAY - 1) ? 1 : 0);
    }
    k_mlp_mfma<<<dim3(256, B_SZ), dim3(256), 0, stream>>>(
        h_hi, h_lo, w1t_hi, w1t_lo, b1, W2, b2, out);
}